// Round 10
// baseline (236.628 us; speedup 1.0000x reference)
//
#include <hip/hip_runtime.h>

typedef unsigned short u16;
typedef __attribute__((ext_vector_type(8))) short short8;   // 8 x bf16 (4 VGPRs)
typedef __attribute__((ext_vector_type(4))) float f32x4;    // MFMA accumulator

__device__ __forceinline__ u16 f2bf(float f){
  union { float f; unsigned u; } v; v.f = f;
  unsigned u = v.u;
  u += 0x7fffu + ((u >> 16) & 1u);   // RNE
  return (u16)(u >> 16);
}
__device__ __forceinline__ float bf2f(u16 h){
  union { unsigned u; float f; } v; v.u = ((unsigned)h) << 16;
  return v.f;
}

// ---------------------------------------------------------------------------
// Kernel 1: MEGA projection.  One block = one (b, hwhi) q-slab (128 q), all
// 256 c, all 3 projections.  x read fp32 directly in fragment pattern
// (64B segments); W cast fp32->bf16 in LDS; outputs written DIRECTLY in
// attention layouts (no separate cast/transpose kernels):
//   theta -> Tq[row][d]:   row = b*1024 + co*8 + hwhi, d = hwlo
//   g     -> Gn[row][ch]:  same mapping (natural [8192][128] V layout)
//   phi   -> K[key][d]:    key = (co&7)*1024 + hw,  d = b*16 + (co>>3)
// grid 64, block 256 (4 waves x 32 q), __launch_bounds__(256,2).
// ---------------------------------------------------------------------------
__global__ __launch_bounds__(256, 2) void megaproj_kernel(
    const float* __restrict__ x,
    const float* __restrict__ tw, const float* __restrict__ tb,
    const float* __restrict__ pw, const float* __restrict__ pb,
    const float* __restrict__ gw, const float* __restrict__ gb,
    u16* __restrict__ Tq, u16* __restrict__ Kk, u16* __restrict__ Gn)
{
  __shared__ __align__(16) u16 Ws[128][136];
  __shared__ __align__(16) u16 Ls[128][136];
  const int qg = blockIdx.x;
  const int b = qg >> 3, hwhi = qg & 7, hw0 = hwhi * 128;
  const int t = threadIdx.x;
  const int wave = t >> 6, lane = t & 63;
  const int quad = lane >> 4, n16 = lane & 15;

  // x fragments (B-operand [q][c]): xf[kc][nt], c = kc*32 + quad*8 + j.
  // Per load: 16 n16-lanes are consecutive hw -> 64B segments.
  short8 xf[8][2];
  #pragma unroll
  for (int kc=0;kc<8;kc++)
    #pragma unroll
    for (int nt=0;nt<2;nt++){
      const int q = wave*32 + nt*16 + n16;
      const float* xs = x + ((size_t)b*256 + kc*32 + quad*8)*1024 + hw0 + q;
      __align__(16) u16 tmp[8];
      #pragma unroll
      for (int j=0;j<8;j++) tmp[j] = f2bf(xs[(size_t)j*1024]);
      xf[kc][nt] = *(short8*)tmp;
    }

  for (int proj=0; proj<3; proj++){
    const float* W    = (proj==0) ? tw : (proj==1) ? pw : gw;
    const float* bias = (proj==0) ? tb : (proj==1) ? pb : gb;

    f32x4 acc[8][2];
    #pragma unroll
    for (int mt=0;mt<8;mt++)
      #pragma unroll
      for (int nt=0;nt<2;nt++){ f32x4 z = {0.f,0.f,0.f,0.f}; acc[mt][nt] = z; }

    for (int half=0; half<2; half++){
      __syncthreads();
      {
        int row = t >> 1, seg = (t & 1) * 64;
        const float* sw = W + (size_t)row*256 + half*128 + seg;
        #pragma unroll
        for (int i=0;i<8;i++){
          float4 a = *(const float4*)(sw + i*8);
          float4 c = *(const float4*)(sw + i*8 + 4);
          __align__(16) u16 t8[8];
          t8[0]=f2bf(a.x); t8[1]=f2bf(a.y); t8[2]=f2bf(a.z); t8[3]=f2bf(a.w);
          t8[4]=f2bf(c.x); t8[5]=f2bf(c.y); t8[6]=f2bf(c.z); t8[7]=f2bf(c.w);
          *(uint4*)&Ws[row][seg + i*8] = *(uint4*)t8;
        }
      }
      __syncthreads();
      #pragma unroll
      for (int kc4=0; kc4<4; kc4++){
        #pragma unroll
        for (int mt=0;mt<8;mt++){
          short8 wf = *(const short8*)&Ws[mt*16 + n16][kc4*32 + quad*8];
          #pragma unroll
          for (int nt=0;nt<2;nt++)
            acc[mt][nt] = __builtin_amdgcn_mfma_f32_16x16x32_bf16(
                            wf, xf[half*4+kc4][nt], acc[mt][nt], 0, 0, 0);
        }
      }
    }

    // epilogue: bias + bf16 into Ls.  theta/g: Ls[co][q].
    // phi: Ls[q][(co&7)*16 + (co>>3)] so K's 16 d-values are contiguous.
    #pragma unroll
    for (int mt=0;mt<8;mt++){
      float4 bv = *(const float4*)&bias[mt*16 + quad*4];
      float bb[4] = {bv.x, bv.y, bv.z, bv.w};
      #pragma unroll
      for (int nt=0;nt<2;nt++){
        const int q = wave*32 + nt*16 + n16;
        #pragma unroll
        for (int r=0;r<4;r++){
          const int co = mt*16 + quad*4 + r;
          u16 v = f2bf(acc[mt][nt][r] + bb[r]);
          if (proj == 1) Ls[q][((co & 7) << 4) | (co >> 3)] = v;
          else           Ls[co][q] = v;
        }
      }
    }
    __syncthreads();

    if (proj == 1){
      // K[key][d]: 1024 (colow,hwlo) pairs, 4/thread; 32B store at d=b*16
      #pragma unroll
      for (int pi=0; pi<4; pi++){
        int p = t*4 + pi;
        int colow = p >> 7, hwlo = p & 127;
        uint4 v0 = *(const uint4*)&Ls[hwlo][colow*16];
        uint4 v1 = *(const uint4*)&Ls[hwlo][colow*16 + 8];
        u16* d = Kk + (size_t)(colow*1024 + hw0 + hwlo)*128 + b*16;
        *(uint4*)d     = v0;
        *(uint4*)(d+8) = v1;
      }
    } else {
      u16* out = (proj==0) ? Tq : Gn;
      int row = t >> 1, seg = (t & 1) * 64;   // row = co
      u16* d = out + (size_t)(b*1024 + row*8 + hwhi)*128 + seg;
      #pragma unroll
      for (int i=0;i<8;i++)
        *(uint4*)(d + i*8) = *(const uint4*)&Ls[row][seg + i*8];
    }
    // next proj's Ls writes are >=2 barriers away (half-loop) -> safe
  }
}

// ---------------------------------------------------------------------------
// Kernel 2: bf16 2D transpose, dst[c][r] = src[r][c].  64x64 tiles.
// Used for Gn [8192][128] -> VT [128][8192].
// ---------------------------------------------------------------------------
__global__ __launch_bounds__(256) void transpose_bf_kernel(
    const u16* __restrict__ src, u16* __restrict__ dst, int R, int C)
{
  __shared__ u16 tile[64][72];
  const int t = threadIdx.x;
  const int c0 = blockIdx.x*64, r0 = blockIdx.y*64;
  {
    int rr = t >> 2, cs = (t & 3) * 16;
    const u16* s = src + (size_t)(r0+rr)*C + c0 + cs;
    uint4 a0 = *(const uint4*)s;
    uint4 a1 = *(const uint4*)(s+8);
    *(uint4*)&tile[rr][cs]   = a0;
    *(uint4*)&tile[rr][cs+8] = a1;
  }
  __syncthreads();
  {
    int cc = t >> 2, rs = (t & 3) * 16;
    __align__(16) u16 tmp[16];
    #pragma unroll
    for (int i=0;i<16;i++) tmp[i] = tile[rs+i][cc];
    u16* d = dst + (size_t)(c0+cc)*R + r0 + rs;
    *(uint4*)d     = *(uint4*)&tmp[0];
    *(uint4*)(d+8) = *(uint4*)&tmp[8];
  }
}

// ---------------------------------------------------------------------------
// Kernel 3: flash attention (no-max softmax), LDS-staged K+V, 64-key tiles,
// key-split S=16, block = 4 waves x 64q, XCD-local (s = bid&15 -> XCD s&7).
// NEW: register prefetch — next tile's K/V loads issue right AFTER barrier2
// (zero outstanding vmem at the barrier, no drain stall) and are consumed
// at the next iteration's LDS write; latency hides under current compute.
// S^T orientation + packed b64 XOR-swizzled P (R9-proven).
// ---------------------------------------------------------------------------
__global__ __launch_bounds__(256, 2) void attn_kernel(
    const u16* __restrict__ Tq, const u16* __restrict__ Kk,
    const u16* __restrict__ Vt, u16* __restrict__ Opart,
    float* __restrict__ lpart)
{
  __shared__ __align__(16) u16 Ks[64][136];    // 17408 B
  __shared__ __align__(16) u16 Vs[128][72];    // 18432 B
  __shared__ __align__(16) u16 Pall[4][4608];  // 4 x [64 q][72]

  const int t = threadIdx.x;
  const int wave = t >> 6, lane = t & 63;
  const int quad = lane >> 4, n16 = lane & 15;
  const int s  = blockIdx.x & 15;
  const int qg = blockIdx.x >> 4;
  const int q0 = qg*256 + wave*64;
  u16* Pw = Pall[wave];
  u16*   Os = Opart + (size_t)s * 1048576;
  float* ls = lpart + (size_t)s * 8192;

  short8 qa[4][4];
  #pragma unroll
  for (int mt=0;mt<4;mt++)
    #pragma unroll
    for (int kc=0;kc<4;kc++)
      qa[mt][kc] = *(const short8*)(Tq + (size_t)(q0 + mt*16 + n16)*128 + kc*32 + quad*8);

  f32x4 o[4][8];
  float lp[4];
  #pragma unroll
  for (int mt=0;mt<4;mt++){
    #pragma unroll
    for (int dt=0;dt<8;dt++){ f32x4 z = {0.f,0.f,0.f,0.f}; o[mt][dt] = z; }
    lp[mt] = 0.f;
  }

  const int krow = t >> 2, kcs = (t & 3) * 32;
  const int vrow = t >> 1, vcs = (t & 1) * 32;
  const int wmask = n16 & 14;

  uint4 kreg[4], vreg[4];
  {
    const int key0 = s*8*64;
    #pragma unroll
    for (int i=0;i<4;i++)
      kreg[i] = *(const uint4*)(Kk + (size_t)(key0 + krow)*128 + kcs + i*8);
    #pragma unroll
    for (int i=0;i<4;i++)
      vreg[i] = *(const uint4*)(Vt + (size_t)vrow*8192 + key0 + vcs + i*8);
  }

  for (int kt = s*8; kt < s*8 + 8; kt++){
    __syncthreads();                 // barrier1: prior tile consumed (drains prefetch too — post-compute, free)
    #pragma unroll
    for (int i=0;i<4;i++) *(uint4*)&Ks[krow][kcs + i*8] = kreg[i];
    #pragma unroll
    for (int i=0;i<4;i++) *(uint4*)&Vs[vrow][vcs + i*8] = vreg[i];
    __syncthreads();                 // barrier2: LDS visible; no vmem outstanding
    if (kt + 1 < s*8 + 8){           // issue next tile's loads NOW (hidden under compute)
      const int key0 = (kt+1)*64;
      #pragma unroll
      for (int i=0;i<4;i++)
        kreg[i] = *(const uint4*)(Kk + (size_t)(key0 + krow)*128 + kcs + i*8);
      #pragma unroll
      for (int i=0;i<4;i++)
        vreg[i] = *(const uint4*)(Vt + (size_t)vrow*8192 + key0 + vcs + i*8);
    }

    // S^T = K Q^T per 16-key block; exp; packed b64 P-writes
    #pragma unroll
    for (int ntk=0; ntk<4; ntk++){
      short8 kf[4];
      #pragma unroll
      for (int kc=0;kc<4;kc++)
        kf[kc] = *(const short8*)&Ks[ntk*16 + n16][kc*32 + quad*8];
      #pragma unroll
      for (int mtq=0;mtq<4;mtq++){
        f32x4 sa = {0.f,0.f,0.f,0.f};
        #pragma unroll
        for (int kc=0;kc<4;kc++)
          sa = __builtin_amdgcn_mfma_f32_16x16x32_bf16(kf[kc], qa[mtq][kc], sa, 0, 0, 0);
        u16 pb[4];
        #pragma unroll
        for (int r=0;r<4;r++){
          float pe = exp2f(sa[r] * 1.4426950408889634f);
          lp[mtq] += pe;
          pb[r] = f2bf(pe);
        }
        uint2 pk;
        pk.x = ((unsigned)pb[1] << 16) | pb[0];
        pk.y = ((unsigned)pb[3] << 16) | pb[2];
        *(uint2*)(Pw + (mtq*16 + n16)*72 + (((ntk*4 + quad) ^ wmask) << 2)) = pk;
      }
    }

    // drain DS: cross-lane P writes must land before cross-lane P reads
    __builtin_amdgcn_s_waitcnt(0xC07F);

    // O~ += P V, per 32-key half
    #pragma unroll
    for (int kb=0; kb<2; kb++){
      short8 pf[4];
      #pragma unroll
      for (int mtq=0;mtq<4;mtq++)
        pf[mtq] = *(const short8*)(Pw + (mtq*16 + n16)*72 + (((kb*8 + quad*2) ^ wmask) << 2));
      #pragma unroll
      for (int dt=0; dt<8; dt++){
        short8 vfd = *(const short8*)&Vs[dt*16 + n16][kb*32 + quad*8];
        #pragma unroll
        for (int mtq=0;mtq<4;mtq++)
          o[mtq][dt] = __builtin_amdgcn_mfma_f32_16x16x32_bf16(pf[mtq], vfd, o[mtq][dt], 0, 0, 0);
      }
    }
  }

  // l: sum across the 4 quads (lane bits 4,5)
  float l[4];
  #pragma unroll
  for (int mt=0;mt<4;mt++){
    float v = lp[mt];
    v += __shfl_xor(v, 16, 64);
    v += __shfl_xor(v, 32, 64);
    l[mt] = v;
  }

  // Epilogue: UNNORMALIZED bf16 partials, lane-packed [row][n16*8+dt]
  #pragma unroll
  for (int mt=0;mt<4;mt++){
    #pragma unroll
    for (int r=0;r<4;r++){
      __align__(16) u16 tmp[8];
      #pragma unroll
      for (int dt=0;dt<8;dt++) tmp[dt] = f2bf(o[mt][dt][r]);
      *(uint4*)(Os + (size_t)(q0 + mt*16 + quad*4 + r)*128 + n16*8) = *(uint4*)tmp;
    }
    if (lane < 16)
      ls[q0 + mt*16 + lane] = l[mt];
  }
}

// ---------------------------------------------------------------------------
// Kernel 3b: merge partials -> OmT in CONV layout [q][j], normalized bf16.
// (R8/R9-proven.)  grid 128 x 256.
// ---------------------------------------------------------------------------
__global__ __launch_bounds__(256) void merge_o_kernel(
    const u16* __restrict__ Opart, const float* __restrict__ lpart, int S,
    u16* __restrict__ OmT)
{
  __shared__ u16 Tm[64][136];
  __shared__ float lrow[64];
  const int t = threadIdx.x;
  const int row0 = blockIdx.x * 64;
  const int b  = row0 >> 10;
  const int j0 = (row0 >> 3) & 127;

  if (t < 64){
    float v = 0.f;
    for (int sp=0; sp<S; sp++) v += lpart[sp*8192 + row0 + t];
    lrow[t] = 1.0f / v;
  }

  const int rl = t >> 2;
  const int cb = (t & 3) * 32;
  float acc[32];
  #pragma unroll
  for (int j=0;j<32;j++) acc[j] = 0.f;
  for (int sp=0; sp<S; sp++){
    const u16* p = Opart + (size_t)sp*1048576 + (size_t)(row0 + rl)*128 + cb;
    #pragma unroll
    for (int q=0;q<4;q++){
      ushort4 v = *(const ushort4*)(p + q*8);
      ushort4 w = *(const ushort4*)(p + q*8 + 4);
      acc[q*8+0] += bf2f(v.x); acc[q*8+1] += bf2f(v.y);
      acc[q*8+2] += bf2f(v.z); acc[q*8+3] += bf2f(v.w);
      acc[q*8+4] += bf2f(w.x); acc[q*8+5] += bf2f(w.y);
      acc[q*8+6] += bf2f(w.z); acc[q*8+7] += bf2f(w.w);
    }
  }
  __syncthreads();
  const float inv = lrow[rl];
  #pragma unroll
  for (int j=0;j<32;j++){
    int cp = cb + j;
    int ch = (cp & 7)*16 + (cp >> 3);
    Tm[rl][ch] = f2bf(acc[j] * inv);
  }
  __syncthreads();
  {
    const int hwhi = t >> 5;
    const int chb  = (t & 31) * 4;
    #pragma unroll
    for (int c=0;c<4;c++){
      int ch = chb + c;
      __align__(16) u16 tmp[8];
      #pragma unroll
      for (int jl=0;jl<8;jl++) tmp[jl] = Tm[jl*8 + hwhi][ch];
      *(uint4*)(OmT + (size_t)(b*1024 + hwhi*128 + ch)*128 + j0) = *(uint4*)tmp;
    }
  }
}

// ---------------------------------------------------------------------------
// Kernel 4: final conv as MFMA + bias + residual (fp32 out).  (R9-proven.)
// grid (4 co-tiles, 64 qg).
// ---------------------------------------------------------------------------
__global__ __launch_bounds__(256, 2) void final_mfma_kernel(
    const float* __restrict__ Ww, const float* __restrict__ Wb,
    const u16* __restrict__ OmT, const float* __restrict__ x,
    float* __restrict__ outp)
{
  __shared__ __align__(16) u16 Ws[64][136];
  __shared__ __align__(16) u16 Os[128][136];
  const int co0 = blockIdx.x * 64, qg = blockIdx.y;
  const int b = qg >> 3, hw0 = (qg & 7) * 128;
  const int q0 = qg * 128;
  const int t = threadIdx.x;
  const int wave = t >> 6, lane = t & 63;
  const int quad = lane >> 4, n16 = lane & 15;

  {
    int row = t >> 2, cbf = (t & 3) * 32;
    const float* sw = Ww + (size_t)(co0 + row)*128 + cbf;
    #pragma unroll
    for (int i=0;i<8;i++){
      float4 v = *(const float4*)(sw + i*4);
      u16* d = &Ws[row][cbf + i*4];
      d[0]=f2bf(v.x); d[1]=f2bf(v.y); d[2]=f2bf(v.z); d[3]=f2bf(v.w);
    }
  }
  {
    int row = t >> 1, cb = (t & 1) * 64;
    const u16* so = OmT + (size_t)(q0 + row)*128 + cb;
    #pragma unroll
    for (int i=0;i<8;i++)
      *(uint4*)&Os[row][cb + i*8] = *(const uint4*)(so + i*8);
  }
  __syncthreads();

  f32x4 acc[4][2];
  #pragma unroll
  for (int mt=0;mt<4;mt++)
    #pragma unroll
    for (int nt=0;nt<2;nt++){ f32x4 z = {0.f,0.f,0.f,0.f}; acc[mt][nt] = z; }

  #pragma unroll
  for (int kc=0; kc<4; kc++){
    short8 xf[2];
    #pragma unroll
    for (int nt=0;nt<2;nt++)
      xf[nt] = *(const short8*)&Os[wave*32 + nt*16 + n16][kc*32 + quad*8];
    #pragma unroll
    for (int mt=0;mt<4;mt++){
      short8 wf = *(const short8*)&Ws[mt*16 + n16][kc*32 + quad*8];
      #pragma unroll
      for (int nt=0;nt<2;nt++)
        acc[mt][nt] = __builtin_amdgcn_mfma_f32_16x16x32_bf16(wf, xf[nt], acc[mt][nt], 0, 0, 0);
    }
  }

  #pragma unroll
  for (int mt=0;mt<4;mt++){
    float4 bv = *(const float4*)&Wb[co0 + mt*16 + quad*4];
    float bb[4] = {bv.x, bv.y, bv.z, bv.w};
    #pragma unroll
    for (int nt=0;nt<2;nt++)
      #pragma unroll
      for (int r=0;r<4;r++){
        size_t idx = (size_t)b*262144 + (size_t)(co0 + mt*16 + quad*4 + r)*1024
                   + hw0 + wave*32 + nt*16 + n16;
        outp[idx] = acc[mt][nt][r] + bb[r] + x[idx];
      }
  }
}

// ---------------------------------------------------------------------------
extern "C" void kernel_launch(void* const* d_in, const int* in_sizes, int n_in,
                              void* d_out, int out_size, void* d_ws, size_t ws_size,
                              hipStream_t stream)
{
  (void)in_sizes; (void)n_in; (void)out_size; (void)ws_size;
  const float* x  = (const float*)d_in[0];
  const float* tw = (const float*)d_in[1];
  const float* tb = (const float*)d_in[2];
  const float* pw = (const float*)d_in[3];
  const float* pb = (const float*)d_in[4];
  const float* gw = (const float*)d_in[5];
  const float* gb = (const float*)d_in[6];
  const float* Ww = (const float*)d_in[7];
  const float* Wb = (const float*)d_in[8];
  float* outp = (float*)d_out;

  char* ws = (char*)d_ws;
  const size_t MB = 1u << 20;
  u16*   Tbf   = (u16*)(ws);            // 2 MB  Tq  [8192][128] (Q layout)
  float* lpart = (float*)(ws + 2*MB);   // 512 KB
  u16*   Gbf   = (u16*)(ws + 4*MB);     // 2 MB  Gn  [8192][128] (V natural)
  u16*   Kbf   = (u16*)(ws + 6*MB);     // 2 MB  K   [8192][128]
  u16*   VTbf  = (u16*)(ws + 8*MB);     // 2 MB  VT  [128][8192]
  u16*   Opart = (u16*)(ws + 10*MB);    // 16 x 2 MB bf16 partials
  u16*   OmT   = (u16*)(ws + 4*MB);     // 2 MB merged O, conv [q][j] (Gn dead)

  megaproj_kernel<<<dim3(64), 256, 0, stream>>>(x, tw, tb, pw, pb, gw, gb,
                                                Tbf, Kbf, Gbf);
  transpose_bf_kernel<<<dim3(2, 128), 256, 0, stream>>>(Gbf, VTbf, 8192, 128);
  attn_kernel<<<dim3(512), 256, 0, stream>>>(Tbf, Kbf, VTbf, Opart, lpart);
  merge_o_kernel<<<dim3(128), 256, 0, stream>>>(Opart, lpart, 16, OmT);
  final_mfma_kernel<<<dim3(4, 64), 256, 0, stream>>>(Ww, Wb, OmT, x, outp);
}

// Round 12
// 196.717 us; speedup vs baseline: 1.2029x; 1.2029x over previous
//
#include <hip/hip_runtime.h>

typedef unsigned short u16;
typedef __attribute__((ext_vector_type(8))) short short8;   // 8 x bf16 (4 VGPRs)
typedef __attribute__((ext_vector_type(4))) float f32x4;    // MFMA accumulator
typedef __attribute__((ext_vector_type(4))) unsigned int uv4; // native u32x4 (nt-store ok)

__device__ __forceinline__ u16 f2bf(float f){
  union { float f; unsigned u; } v; v.f = f;
  unsigned u = v.u;
  u += 0x7fffu + ((u >> 16) & 1u);   // RNE
  return (u16)(u >> 16);
}
__device__ __forceinline__ float bf2f(u16 h){
  union { unsigned u; float f; } v; v.u = ((unsigned)h) << 16;
  return v.f;
}

// ---------------------------------------------------------------------------
// Kernel 1: direct-layout projection, ONE proj per block (grid 3 x 64 => 192
// blocks, 75% CU occupancy).  Block = (proj, b, hwhi): 128 q x 128 co x K=256.
// x read fp32 directly in fragment pattern (64B segments), W cast
// fp32->bf16 through LDS.  Outputs written DIRECTLY in attention layouts:
//   theta -> Tq[row][d]:  row = b*1024 + co*8 + hwhi, d = hwlo
//   g     -> Gn[row][ch]: same mapping
//   phi   -> K[key][d]:   key = (co&7)*1024 + hw, d = b*16 + (co>>3)
// ---------------------------------------------------------------------------
__global__ __launch_bounds__(256, 2) void proj_dir_kernel(
    const float* __restrict__ x,
    const float* __restrict__ tw, const float* __restrict__ tb,
    const float* __restrict__ pw, const float* __restrict__ pb,
    const float* __restrict__ gw, const float* __restrict__ gb,
    u16* __restrict__ Tq, u16* __restrict__ Kk, u16* __restrict__ Gn)
{
  __shared__ __align__(16) u16 Ws[128][136];
  __shared__ __align__(16) u16 Ls[128][136];
  const int proj = blockIdx.x;
  const int qg = blockIdx.y;
  const int b = qg >> 3, hwhi = qg & 7, hw0 = hwhi * 128;
  const int t = threadIdx.x;
  const int wave = t >> 6, lane = t & 63;
  const int quad = lane >> 4, n16 = lane & 15;
  const float* W    = (proj==0) ? tw : (proj==1) ? pw : gw;
  const float* bias = (proj==0) ? tb : (proj==1) ? pb : gb;

  // x fragments (B-operand [q][c]): c = kc*32 + quad*8 + j; 64B segments.
  short8 xf[8][2];
  #pragma unroll
  for (int kc=0;kc<8;kc++)
    #pragma unroll
    for (int nt=0;nt<2;nt++){
      const int q = wave*32 + nt*16 + n16;
      const float* xs = x + ((size_t)b*256 + kc*32 + quad*8)*1024 + hw0 + q;
      __align__(16) u16 tmp[8];
      #pragma unroll
      for (int j=0;j<8;j++) tmp[j] = f2bf(xs[(size_t)j*1024]);
      xf[kc][nt] = *(short8*)tmp;
    }

  f32x4 acc[8][2];
  #pragma unroll
  for (int mt=0;mt<8;mt++)
    #pragma unroll
    for (int nt=0;nt<2;nt++){ f32x4 z = {0.f,0.f,0.f,0.f}; acc[mt][nt] = z; }

  for (int half=0; half<2; half++){
    __syncthreads();
    {
      int row = t >> 1, seg = (t & 1) * 64;
      const float* sw = W + (size_t)row*256 + half*128 + seg;
      #pragma unroll
      for (int i=0;i<8;i++){
        float4 a = *(const float4*)(sw + i*8);
        float4 c = *(const float4*)(sw + i*8 + 4);
        __align__(16) u16 t8[8];
        t8[0]=f2bf(a.x); t8[1]=f2bf(a.y); t8[2]=f2bf(a.z); t8[3]=f2bf(a.w);
        t8[4]=f2bf(c.x); t8[5]=f2bf(c.y); t8[6]=f2bf(c.z); t8[7]=f2bf(c.w);
        *(uint4*)&Ws[row][seg + i*8] = *(uint4*)t8;
      }
    }
    __syncthreads();
    #pragma unroll
    for (int kc4=0; kc4<4; kc4++){
      #pragma unroll
      for (int mt=0;mt<8;mt++){
        short8 wf = *(const short8*)&Ws[mt*16 + n16][kc4*32 + quad*8];
        #pragma unroll
        for (int nt=0;nt<2;nt++)
          acc[mt][nt] = __builtin_amdgcn_mfma_f32_16x16x32_bf16(
                          wf, xf[half*4+kc4][nt], acc[mt][nt], 0, 0, 0);
      }
    }
  }

  // epilogue: bias + bf16 into Ls.  theta/g: Ls[co][q];
  // phi: Ls[q][(co&7)*16 + (co>>3)] so K's 16 d-values are contiguous.
  #pragma unroll
  for (int mt=0;mt<8;mt++){
    float4 bv = *(const float4*)&bias[mt*16 + quad*4];
    float bb[4] = {bv.x, bv.y, bv.z, bv.w};
    #pragma unroll
    for (int nt=0;nt<2;nt++){
      const int q = wave*32 + nt*16 + n16;
      #pragma unroll
      for (int r=0;r<4;r++){
        const int co = mt*16 + quad*4 + r;
        u16 v = f2bf(acc[mt][nt][r] + bb[r]);
        if (proj == 1) Ls[q][((co & 7) << 4) | (co >> 3)] = v;
        else           Ls[co][q] = v;
      }
    }
  }
  __syncthreads();

  if (proj == 1){
    // K[key][d]: 1024 (colow,hwlo) pairs, 4/thread; 32B store at d=b*16
    #pragma unroll
    for (int pi=0; pi<4; pi++){
      int p = t*4 + pi;
      int colow = p >> 7, hwlo = p & 127;
      uint4 v0 = *(const uint4*)&Ls[hwlo][colow*16];
      uint4 v1 = *(const uint4*)&Ls[hwlo][colow*16 + 8];
      u16* d = Kk + (size_t)(colow*1024 + hw0 + hwlo)*128 + b*16;
      *(uint4*)d     = v0;
      *(uint4*)(d+8) = v1;
    }
  } else {
    u16* out = (proj==0) ? Tq : Gn;
    int row = t >> 1, seg = (t & 1) * 64;   // row = co
    u16* d = out + (size_t)(b*1024 + row*8 + hwhi)*128 + seg;
    #pragma unroll
    for (int i=0;i<8;i++)
      *(uint4*)(d + i*8) = *(const uint4*)&Ls[row][seg + i*8];
  }
}

// ---------------------------------------------------------------------------
// Kernel 2: bf16 2D transpose, dst[c][r] = src[r][c].  64x64 tiles.
// Used for Gn [8192][128] -> VT [128][8192].
// ---------------------------------------------------------------------------
__global__ __launch_bounds__(256) void transpose_bf_kernel(
    const u16* __restrict__ src, u16* __restrict__ dst, int R, int C)
{
  __shared__ u16 tile[64][72];
  const int t = threadIdx.x;
  const int c0 = blockIdx.x*64, r0 = blockIdx.y*64;
  {
    int rr = t >> 2, cs = (t & 3) * 16;
    const u16* s = src + (size_t)(r0+rr)*C + c0 + cs;
    uint4 a0 = *(const uint4*)s;
    uint4 a1 = *(const uint4*)(s+8);
    *(uint4*)&tile[rr][cs]   = a0;
    *(uint4*)&tile[rr][cs+8] = a1;
  }
  __syncthreads();
  {
    int cc = t >> 2, rs = (t & 3) * 16;
    __align__(16) u16 tmp[16];
    #pragma unroll
    for (int i=0;i<16;i++) tmp[i] = tile[rs+i][cc];
    u16* d = dst + (size_t)(c0+cc)*R + r0 + rs;
    *(uint4*)d     = *(uint4*)&tmp[0];
    *(uint4*)(d+8) = *(uint4*)&tmp[8];
  }
}

// ---------------------------------------------------------------------------
// Kernel 3: flash attention — EXACT R9 structure (80 µs proven; R10's
// register prefetch spilled to scratch).  Only change vs R9:
// NON-TEMPORAL partial stores (write-once stream, keeps K/V/Tq in L2).
// No-max softmax, LDS-staged K+V, 64-key tiles, S=16, 4 waves x 64q,
// XCD-local (s = bid&15 -> XCD s&7).  S^T + packed b64 XOR-swizzled P.
// ---------------------------------------------------------------------------
__global__ __launch_bounds__(256, 2) void attn_kernel(
    const u16* __restrict__ Tq, const u16* __restrict__ Kk,
    const u16* __restrict__ Vt, u16* __restrict__ Opart,
    float* __restrict__ lpart)
{
  __shared__ __align__(16) u16 Ks[64][136];    // 17408 B
  __shared__ __align__(16) u16 Vs[128][72];    // 18432 B
  __shared__ __align__(16) u16 Pall[4][4608];  // 4 x [64 q][72]

  const int t = threadIdx.x;
  const int wave = t >> 6, lane = t & 63;
  const int quad = lane >> 4, n16 = lane & 15;
  const int s  = blockIdx.x & 15;
  const int qg = blockIdx.x >> 4;
  const int q0 = qg*256 + wave*64;
  u16* Pw = Pall[wave];
  u16*   Os = Opart + (size_t)s * 1048576;
  float* ls = lpart + (size_t)s * 8192;

  short8 qa[4][4];
  #pragma unroll
  for (int mt=0;mt<4;mt++)
    #pragma unroll
    for (int kc=0;kc<4;kc++)
      qa[mt][kc] = *(const short8*)(Tq + (size_t)(q0 + mt*16 + n16)*128 + kc*32 + quad*8);

  f32x4 o[4][8];
  float lp[4];
  #pragma unroll
  for (int mt=0;mt<4;mt++){
    #pragma unroll
    for (int dt=0;dt<8;dt++){ f32x4 z = {0.f,0.f,0.f,0.f}; o[mt][dt] = z; }
    lp[mt] = 0.f;
  }

  const int krow = t >> 2, kcs = (t & 3) * 32;
  const int vrow = t >> 1, vcs = (t & 1) * 32;
  const int wmask = n16 & 14;

  for (int kt = s*8; kt < s*8 + 8; kt++){
    const int key0 = kt * 64;
    __syncthreads();
    #pragma unroll
    for (int i=0;i<4;i++)
      *(uint4*)&Ks[krow][kcs + i*8] =
        *(const uint4*)(Kk + (size_t)(key0 + krow)*128 + kcs + i*8);
    #pragma unroll
    for (int i=0;i<4;i++)
      *(uint4*)&Vs[vrow][vcs + i*8] =
        *(const uint4*)(Vt + (size_t)vrow*8192 + key0 + vcs + i*8);
    __syncthreads();

    // S^T = K Q^T per 16-key block; exp; packed b64 P-writes
    #pragma unroll
    for (int ntk=0; ntk<4; ntk++){
      short8 kf[4];
      #pragma unroll
      for (int kc=0;kc<4;kc++)
        kf[kc] = *(const short8*)&Ks[ntk*16 + n16][kc*32 + quad*8];
      #pragma unroll
      for (int mtq=0;mtq<4;mtq++){
        f32x4 sa = {0.f,0.f,0.f,0.f};
        #pragma unroll
        for (int kc=0;kc<4;kc++)
          sa = __builtin_amdgcn_mfma_f32_16x16x32_bf16(kf[kc], qa[mtq][kc], sa, 0, 0, 0);
        u16 pb[4];
        #pragma unroll
        for (int r=0;r<4;r++){
          float pe = exp2f(sa[r] * 1.4426950408889634f);
          lp[mtq] += pe;
          pb[r] = f2bf(pe);
        }
        uint2 pk;
        pk.x = ((unsigned)pb[1] << 16) | pb[0];
        pk.y = ((unsigned)pb[3] << 16) | pb[2];
        *(uint2*)(Pw + (mtq*16 + n16)*72 + (((ntk*4 + quad) ^ wmask) << 2)) = pk;
      }
    }

    // drain DS: cross-lane P writes must land before cross-lane P reads
    __builtin_amdgcn_s_waitcnt(0xC07F);

    // O~ += P V, per 32-key half
    #pragma unroll
    for (int kb=0; kb<2; kb++){
      short8 pf[4];
      #pragma unroll
      for (int mtq=0;mtq<4;mtq++)
        pf[mtq] = *(const short8*)(Pw + (mtq*16 + n16)*72 + (((kb*8 + quad*2) ^ wmask) << 2));
      #pragma unroll
      for (int dt=0; dt<8; dt++){
        short8 vfd = *(const short8*)&Vs[dt*16 + n16][kb*32 + quad*8];
        #pragma unroll
        for (int mtq=0;mtq<4;mtq++)
          o[mtq][dt] = __builtin_amdgcn_mfma_f32_16x16x32_bf16(pf[mtq], vfd, o[mtq][dt], 0, 0, 0);
      }
    }
  }

  // l: sum across the 4 quads (lane bits 4,5)
  float l[4];
  #pragma unroll
  for (int mt=0;mt<4;mt++){
    float v = lp[mt];
    v += __shfl_xor(v, 16, 64);
    v += __shfl_xor(v, 32, 64);
    l[mt] = v;
  }

  // Epilogue: UNNORMALIZED bf16 partials, lane-packed [row][n16*8+dt],
  // NON-TEMPORAL (write-once stream; don't evict K/V/Tq from L2).
  // uv4 = native ext_vector (HIP's uint4 class is rejected by the builtin).
  #pragma unroll
  for (int mt=0;mt<4;mt++){
    #pragma unroll
    for (int r=0;r<4;r++){
      __align__(16) u16 tmp[8];
      #pragma unroll
      for (int dt=0;dt<8;dt++) tmp[dt] = f2bf(o[mt][dt][r]);
      __builtin_nontemporal_store(*(uv4*)tmp,
        (uv4*)(Os + (size_t)(q0 + mt*16 + quad*4 + r)*128 + n16*8));
    }
    if (lane < 16)
      __builtin_nontemporal_store(l[mt], &ls[q0 + mt*16 + lane]);
  }
}

// ---------------------------------------------------------------------------
// Kernel 3b: merge partials -> OmT in CONV layout [q][j], normalized bf16.
// (R8/R9-proven.)  grid 128 x 256.
// ---------------------------------------------------------------------------
__global__ __launch_bounds__(256) void merge_o_kernel(
    const u16* __restrict__ Opart, const float* __restrict__ lpart, int S,
    u16* __restrict__ OmT)
{
  __shared__ u16 Tm[64][136];
  __shared__ float lrow[64];
  const int t = threadIdx.x;
  const int row0 = blockIdx.x * 64;
  const int b  = row0 >> 10;
  const int j0 = (row0 >> 3) & 127;

  if (t < 64){
    float v = 0.f;
    for (int sp=0; sp<S; sp++) v += lpart[sp*8192 + row0 + t];
    lrow[t] = 1.0f / v;
  }

  const int rl = t >> 2;
  const int cb = (t & 3) * 32;
  float acc[32];
  #pragma unroll
  for (int j=0;j<32;j++) acc[j] = 0.f;
  for (int sp=0; sp<S; sp++){
    const u16* p = Opart + (size_t)sp*1048576 + (size_t)(row0 + rl)*128 + cb;
    #pragma unroll
    for (int q=0;q<4;q++){
      ushort4 v = *(const ushort4*)(p + q*8);
      ushort4 w = *(const ushort4*)(p + q*8 + 4);
      acc[q*8+0] += bf2f(v.x); acc[q*8+1] += bf2f(v.y);
      acc[q*8+2] += bf2f(v.z); acc[q*8+3] += bf2f(v.w);
      acc[q*8+4] += bf2f(w.x); acc[q*8+5] += bf2f(w.y);
      acc[q*8+6] += bf2f(w.z); acc[q*8+7] += bf2f(w.w);
    }
  }
  __syncthreads();
  const float inv = lrow[rl];
  #pragma unroll
  for (int j=0;j<32;j++){
    int cp = cb + j;
    int ch = (cp & 7)*16 + (cp >> 3);
    Tm[rl][ch] = f2bf(acc[j] * inv);
  }
  __syncthreads();
  {
    const int hwhi = t >> 5;
    const int chb  = (t & 31) * 4;
    #pragma unroll
    for (int c=0;c<4;c++){
      int ch = chb + c;
      __align__(16) u16 tmp[8];
      #pragma unroll
      for (int jl=0;jl<8;jl++) tmp[jl] = Tm[jl*8 + hwhi][ch];
      *(uint4*)(OmT + (size_t)(b*1024 + hwhi*128 + ch)*128 + j0) = *(uint4*)tmp;
    }
  }
}

// ---------------------------------------------------------------------------
// Kernel 4: final conv as MFMA + bias + residual (fp32 out).  (R9-proven.)
// grid (4 co-tiles, 64 qg).
// ---------------------------------------------------------------------------
__global__ __launch_bounds__(256, 2) void final_mfma_kernel(
    const float* __restrict__ Ww, const float* __restrict__ Wb,
    const u16* __restrict__ OmT, const float* __restrict__ x,
    float* __restrict__ outp)
{
  __shared__ __align__(16) u16 Ws[64][136];
  __shared__ __align__(16) u16 Os[128][136];
  const int co0 = blockIdx.x * 64, qg = blockIdx.y;
  const int b = qg >> 3, hw0 = (qg & 7) * 128;
  const int q0 = qg * 128;
  const int t = threadIdx.x;
  const int wave = t >> 6, lane = t & 63;
  const int quad = lane >> 4, n16 = lane & 15;

  {
    int row = t >> 2, cbf = (t & 3) * 32;
    const float* sw = Ww + (size_t)(co0 + row)*128 + cbf;
    #pragma unroll
    for (int i=0;i<8;i++){
      float4 v = *(const float4*)(sw + i*4);
      u16* d = &Ws[row][cbf + i*4];
      d[0]=f2bf(v.x); d[1]=f2bf(v.y); d[2]=f2bf(v.z); d[3]=f2bf(v.w);
    }
  }
  {
    int row = t >> 1, cb = (t & 1) * 64;
    const u16* so = OmT + (size_t)(q0 + row)*128 + cb;
    #pragma unroll
    for (int i=0;i<8;i++)
      *(uint4*)&Os[row][cb + i*8] = *(const uint4*)(so + i*8);
  }
  __syncthreads();

  f32x4 acc[4][2];
  #pragma unroll
  for (int mt=0;mt<4;mt++)
    #pragma unroll
    for (int nt=0;nt<2;nt++){ f32x4 z = {0.f,0.f,0.f,0.f}; acc[mt][nt] = z; }

  #pragma unroll
  for (int kc=0; kc<4; kc++){
    short8 xf[2];
    #pragma unroll
    for (int nt=0;nt<2;nt++)
      xf[nt] = *(const short8*)&Os[wave*32 + nt*16 + n16][kc*32 + quad*8];
    #pragma unroll
    for (int mt=0;mt<4;mt++){
      short8 wf = *(const short8*)&Ws[mt*16 + n16][kc*32 + quad*8];
      #pragma unroll
      for (int nt=0;nt<2;nt++)
        acc[mt][nt] = __builtin_amdgcn_mfma_f32_16x16x32_bf16(wf, xf[nt], acc[mt][nt], 0, 0, 0);
    }
  }

  #pragma unroll
  for (int mt=0;mt<4;mt++){
    float4 bv = *(const float4*)&Wb[co0 + mt*16 + quad*4];
    float bb[4] = {bv.x, bv.y, bv.z, bv.w};
    #pragma unroll
    for (int nt=0;nt<2;nt++)
      #pragma unroll
      for (int r=0;r<4;r++){
        size_t idx = (size_t)b*262144 + (size_t)(co0 + mt*16 + quad*4 + r)*1024
                   + hw0 + wave*32 + nt*16 + n16;
        outp[idx] = acc[mt][nt][r] + bb[r] + x[idx];
      }
  }
}

// ---------------------------------------------------------------------------
extern "C" void kernel_launch(void* const* d_in, const int* in_sizes, int n_in,
                              void* d_out, int out_size, void* d_ws, size_t ws_size,
                              hipStream_t stream)
{
  (void)in_sizes; (void)n_in; (void)out_size; (void)ws_size;
  const float* x  = (const float*)d_in[0];
  const float* tw = (const float*)d_in[1];
  const float* tb = (const float*)d_in[2];
  const float* pw = (const float*)d_in[3];
  const float* pb = (const float*)d_in[4];
  const float* gw = (const float*)d_in[5];
  const float* gb = (const float*)d_in[6];
  const float* Ww = (const float*)d_in[7];
  const float* Wb = (const float*)d_in[8];
  float* outp = (float*)d_out;

  char* ws = (char*)d_ws;
  const size_t MB = 1u << 20;
  u16*   Tbf   = (u16*)(ws);            // 2 MB  Tq  [8192][128] (Q layout)
  float* lpart = (float*)(ws + 2*MB);   // 512 KB
  u16*   Gbf   = (u16*)(ws + 4*MB);     // 2 MB  Gn  [8192][128] (V natural)
  u16*   Kbf   = (u16*)(ws + 6*MB);     // 2 MB  K   [8192][128]
  u16*   VTbf  = (u16*)(ws + 8*MB);     // 2 MB  VT  [128][8192]
  u16*   Opart = (u16*)(ws + 10*MB);    // 16 x 2 MB bf16 partials
  u16*   OmT   = (u16*)(ws + 4*MB);     // 2 MB merged O, conv [q][j] (Gn dead)

  proj_dir_kernel<<<dim3(3, 64), 256, 0, stream>>>(x, tw, tb, pw, pb, gw, gb,
                                                   Tbf, Kbf, Gbf);
  transpose_bf_kernel<<<dim3(2, 128), 256, 0, stream>>>(Gbf, VTbf, 8192, 128);
  attn_kernel<<<dim3(512), 256, 0, stream>>>(Tbf, Kbf, VTbf, Opart, lpart);
  merge_o_kernel<<<dim3(128), 256, 0, stream>>>(Opart, lpart, 16, OmT);
  final_mfma_kernel<<<dim3(4, 64), 256, 0, stream>>>(Ww, Wb, OmT, x, outp);
}